// Round 7
// baseline (102.765 us; speedup 1.0000x reference)
//
#include <hip/hip_runtime.h>

// RainKAN fused forward via MFMA f16, LDS-staged double-buffered B-fragments.
//   X[B, K=2048pad] x W[K,64] -> h[B,64] -> exact fp32 KAN layer 2 -> out[B]
// K-steps 0..63 (32 k each; step 63 zero pad). Steps 0..6: silu slots (input i = st*32+kg*8+j).
// Steps 7..63: spline slots (input i = (st-7)*4+kg, basis j) -> A-frag built in registers
// from one LDS x read per step (all 8 bases of one x).
// Block: M=32 samples, 256 threads, wave (mh,kh) = m-tile mh x K-parity kh.
// B pipeline: 4-step chunks (16 KB), double-buffered in LDS. Per chunk, wave w loads step
// (4c+w)'s 4 KB from wcat (4 coalesced dwordx4), consumes previous chunk from LDS
// (ds_read_b128 - no L2 latency on the consume path), then ds_writes + barrier.
// Global B volume: 512 blocks x 256 KB = 134 MB (half of R6), fetched once per block.
// W prepped into d_ws fp16 B-frag order: elem(st,nt,lane,j)=W[st*32+(lane>>4)*8+j][nt*16+(lane&15)].

typedef _Float16 half8 __attribute__((ext_vector_type(8)));
typedef float floatx4 __attribute__((ext_vector_type(4)));

#define XR 233   // x-row stride in floats (odd -> benign LDS banking)

__device__ __forceinline__ float silu_f(float x) {
    return x / (1.0f + __expf(-x));
}

__device__ __forceinline__ void bspline8_dense(float x, float f[8]) {
    float u  = (x + 2.2f) * 2.5f;
    float fj = floorf(u);
    float t  = u - fj;
    int   j  = (int)fj;
    bool valid = (u >= 0.0f) && (u < 11.0f);
    float t2 = t * t, t3 = t2 * t, omt = 1.0f - t;
    float b0 = omt * omt * omt * (1.0f / 6.0f);
    float b1 = (3.0f * t3 - 6.0f * t2 + 4.0f) * (1.0f / 6.0f);
    float b2 = (-3.0f * t3 + 3.0f * t2 + 3.0f * t + 1.0f) * (1.0f / 6.0f);
    float b3 = t3 * (1.0f / 6.0f);
    if (!valid) { b0 = b1 = b2 = b3 = 0.0f; }
    int base = j - 3;
#pragma unroll
    for (int g = 0; g < 8; ++g) {
        int m = g - base;
        float v = (m == 0) ? b0 : 0.0f;
        v = (m == 1) ? b1 : v;
        v = (m == 2) ? b2 : v;
        v = (m == 3) ? b3 : v;
        f[g] = v;
    }
}

// f16 A-fragment: 4 bases placed at half-slots (j-3)..j via 128-bit shift
__device__ __forceinline__ half8 bspline_frag(float x) {
    float u  = (x + 2.2f) * 2.5f;
    float fj = floorf(u);
    float t  = u - fj;
    int   j  = (int)fj;
    bool valid = (u >= 0.0f) && (u < 11.0f);
    float t2 = t * t, t3 = t2 * t, omt = 1.0f - t;
    float b0 = omt * omt * omt * (1.0f / 6.0f);
    float b1 = (3.0f * t3 - 6.0f * t2 + 4.0f) * (1.0f / 6.0f);
    float b2 = (-3.0f * t3 + 3.0f * t2 + 3.0f * t + 1.0f) * (1.0f / 6.0f);
    float b3 = t3 * (1.0f / 6.0f);
    union { _Float16 h[4]; unsigned long long q; } p;
    p.h[0] = (_Float16)b0; p.h[1] = (_Float16)b1;
    p.h[2] = (_Float16)b2; p.h[3] = (_Float16)b3;
    unsigned long long lo = valid ? p.q : 0ull;
    int jc = valid ? j : 3;
    int sh = (jc - 3) * 16;              // bits, in [-48, 112]
    unsigned long long rlo, rhi;
    if (sh >= 0) {
        rlo = (sh < 64) ? (lo << sh) : 0ull;
        rhi = (sh == 0) ? 0ull
            : (sh < 64) ? (lo >> (64 - sh))
                        : (lo << (sh - 64));
    } else {
        rlo = lo >> (-sh);
        rhi = 0ull;
    }
    union { unsigned long long q[2]; half8 v; } r;
    r.q[0] = rlo; r.q[1] = rhi;
    return r.v;
}

// ---- prep: wb1[219,64] + cf1[219,64,8] -> fp16 B-frag wcat[131072] (256 KB) ----
__global__ __launch_bounds__(256) void build_w(
    const float* __restrict__ wb1, const float* __restrict__ cf1,
    _Float16* __restrict__ wcat)
{
    int flat = blockIdx.x * 256 + threadIdx.x;   // < 64*4*64 = 16384
    int lane = flat & 63;
    int nt   = (flat >> 6) & 3;
    int st   = flat >> 8;                        // 0..63
    int kg   = lane >> 4;
    int n    = nt * 16 + (lane & 15);
    _Float16 v[8];
    if (st < 7) {
#pragma unroll
        for (int j = 0; j < 8; ++j) {
            int i = st * 32 + kg * 8 + j;
            v[j] = (_Float16)((i < 219) ? wb1[i * 64 + n] : 0.0f);
        }
    } else {
        int i = (st - 7) * 4 + kg;
#pragma unroll
        for (int j = 0; j < 8; ++j)
            v[j] = (_Float16)((i < 219) ? cf1[(i * 64 + n) * 8 + j] : 0.0f);
    }
    *(half8*)(wcat + (size_t)flat * 8) = *(half8*)v;
}

// ---- fused GEMM + layer 2: 512 blocks x 256 threads, 32 samples/block ----
__global__ __launch_bounds__(256) void kan_mfma(
    const float* __restrict__ hist,    // [B,192]
    const float* __restrict__ statf,   // [B,3]
    const float* __restrict__ timef,   // [B,8]
    const int*   __restrict__ st_idx,  // [B]
    const float* __restrict__ emb,     // [120,16]
    const _Float16* __restrict__ wcat, // [131072]
    const float* __restrict__ wb2,     // [64]
    const float* __restrict__ cf2,     // [64,8]
    float* __restrict__ out)           // [B]
{
    __shared__ union {
        struct {
            float    xb[32 * XR];        // 29824 B
            _Float16 bst[2][4][2048];    // 32768 B: [buf][step-slot][nt*512+lane*8]
        } mn;                            // 62592 B total
        struct { float h[2][32 * 65]; float part[8 * 32]; } ep;  // 17664 B
    } sm;

    const int tid  = threadIdx.x;
    const int lane = tid & 63;
    const int w    = __builtin_amdgcn_readfirstlane(tid >> 6);
    const int mh   = w & 1;            // m-tile (rows mh*16..+16)
    const int kh   = w >> 1;           // K-step parity within chunk
    const int bx   = blockIdx.x;
    const int row  = lane & 15;
    const int kg   = lane >> 4;

    // ---- stage raw x[32][233] into LDS (slots 219..232 zeroed) ----
    {
        const int s = tid >> 3, c8 = tid & 7;
        const int b = bx * 32 + s;
        const float4* h4 = (const float4*)hist;   // 48 float4 per row
#pragma unroll
        for (int f = 0; f < 6; ++f) {
            int i4 = c8 + 8 * f;                  // 0..47
            float4 v = h4[b * 48 + i4];
            sm.mn.xb[s * XR + i4 * 4 + 0] = v.x;
            sm.mn.xb[s * XR + i4 * 4 + 1] = v.y;
            sm.mn.xb[s * XR + i4 * 4 + 2] = v.z;
            sm.mn.xb[s * XR + i4 * 4 + 3] = v.w;
        }
    }
#pragma unroll
    for (int f = 0; f < 6; ++f) {
        int flat = f * 256 + tid;                 // < 1536 = 32*48
        int s  = flat / 48;
        int ii = 192 + (flat % 48);               // 192..239
        int b  = bx * 32 + s;
        float v;
        if (ii < 195)      v = statf[b * 3 + (ii - 192)];
        else if (ii < 203) v = timef[b * 8 + (ii - 195)];
        else if (ii < 219) v = emb[st_idx[b] * 16 + (ii - 203)];
        else               v = 0.0f;
        if (ii < 233) sm.mn.xb[s * XR + ii] = v;
    }

    // ---- prologue: stage chunk 0 (steps 0..3; wave w stages step w) ----
    half8 rg[4];
    {
        const _Float16* src = wcat + (size_t)w * 2048 + lane * 8;
#pragma unroll
        for (int nt = 0; nt < 4; ++nt) rg[nt] = *(const half8*)(src + nt * 512);
#pragma unroll
        for (int nt = 0; nt < 4; ++nt)
            *(half8*)&sm.mn.bst[0][w][nt * 512 + lane * 8] = rg[nt];
    }
    __syncthreads();

    const float* xrow = &sm.mn.xb[(mh * 16 + row) * XR];

    floatx4 acc[4];
#pragma unroll
    for (int nt = 0; nt < 4; ++nt) acc[nt] = (floatx4){0.f, 0.f, 0.f, 0.f};

    // ---- main pipeline: 16 chunks of 4 steps ----
    for (int c = 0; c < 16; ++c) {
        const int buf = c & 1;
        if (c < 15) {                             // bulk-load next chunk's step (4c+4+w)
            const _Float16* src = wcat + (size_t)(4 * (c + 1) + w) * 2048 + lane * 8;
#pragma unroll
            for (int nt = 0; nt < 4; ++nt) rg[nt] = *(const half8*)(src + nt * 512);
        }
        // consume my 2 steps of chunk c from LDS
#pragma unroll
        for (int u = 0; u < 2; ++u) {
            const int sl = kh + 2 * u;            // step-slot within chunk (uniform)
            const int st = 4 * c + sl;            // global step (uniform)
            half8 af;
            if (st < 7) {
                const int i0 = st * 32 + kg * 8;
#pragma unroll
                for (int jj = 0; jj < 8; ++jj)
                    af[jj] = (_Float16)silu_f(xrow[i0 + jj]);
            } else {
                af = bspline_frag(xrow[(st - 7) * 4 + kg]);
            }
            const _Float16* bp = &sm.mn.bst[buf][sl][lane * 8];
            half8 b0 = *(const half8*)(bp);
            half8 b1 = *(const half8*)(bp + 512);
            half8 b2 = *(const half8*)(bp + 1024);
            half8 b3 = *(const half8*)(bp + 1536);
            acc[0] = __builtin_amdgcn_mfma_f32_16x16x32_f16(af, b0, acc[0], 0, 0, 0);
            acc[1] = __builtin_amdgcn_mfma_f32_16x16x32_f16(af, b1, acc[1], 0, 0, 0);
            acc[2] = __builtin_amdgcn_mfma_f32_16x16x32_f16(af, b2, acc[2], 0, 0, 0);
            acc[3] = __builtin_amdgcn_mfma_f32_16x16x32_f16(af, b3, acc[3], 0, 0, 0);
        }
        if (c < 15) {                             // publish next chunk
#pragma unroll
            for (int nt = 0; nt < 4; ++nt)
                *(half8*)&sm.mn.bst[buf ^ 1][w][nt * 512 + lane * 8] = rg[nt];
        }
        __syncthreads();
    }

    // ---- epilogue: h partials (C/D: col=lane&15, row=(lane>>4)*4+reg) ----
    // last loop barrier guarantees all consumption done; safe to overwrite mn region
#pragma unroll
    for (int nt = 0; nt < 4; ++nt) {
#pragma unroll
        for (int r = 0; r < 4; ++r) {
            const int rr = mh * 16 + kg * 4 + r;  // 0..31
            const int cc = nt * 16 + row;         // 0..63
            sm.ep.h[kh][rr * 65 + cc] = acc[nt][r];
        }
    }
    __syncthreads();

    // ---- exact fp32 layer 2: thread (s = tid&31, og = tid>>5) -> outputs og*8..+8 ----
    {
        const int s  = tid & 31;
        const int og = tid >> 5;
        float psum = 0.0f;
#pragma unroll
        for (int oo = 0; oo < 8; ++oo) {
            const int o = og * 8 + oo;
            float h = sm.ep.h[0][s * 65 + o] + sm.ep.h[1][s * 65 + o];
            psum = fmaf(silu_f(h), wb2[o], psum);
            float f2[8];
            bspline8_dense(h, f2);
#pragma unroll
            for (int g = 0; g < 8; ++g)
                psum = fmaf(f2[g], cf2[o * 8 + g], psum);
        }
        sm.ep.part[og * 32 + s] = psum;
    }
    __syncthreads();
    if (tid < 32) {
        float r = 0.0f;
#pragma unroll
        for (int og = 0; og < 8; ++og) r += sm.ep.part[og * 32 + tid];
        out[bx * 32 + tid] = r;
    }
}

extern "C" void kernel_launch(void* const* d_in, const int* in_sizes, int n_in,
                              void* d_out, int out_size, void* d_ws, size_t ws_size,
                              hipStream_t stream) {
    const float* hist  = (const float*)d_in[0];
    const float* statf = (const float*)d_in[1];
    const float* timef = (const float*)d_in[2];
    const int*   stidx = (const int*)  d_in[3];
    const float* emb   = (const float*)d_in[4];
    const float* wb1   = (const float*)d_in[5];
    const float* cf1   = (const float*)d_in[6];
    const float* wb2   = (const float*)d_in[7];
    const float* cf2   = (const float*)d_in[8];
    float* out = (float*)d_out;

    _Float16* wcat = (_Float16*)d_ws;   // 131072 fp16 = 256 KB

    build_w<<<64, 256, 0, stream>>>(wb1, cf1, wcat);
    kan_mfma<<<512, 256, 0, stream>>>(hist, statf, timef, stidx, emb,
                                      wcat, wb2, cf2, out);
}